// Round 15
// baseline (71.980 us; speedup 1.0000x reference)
//
#include <hip/hip_runtime.h>

typedef __attribute__((ext_vector_type(4))) _Float16 half4;
typedef __attribute__((ext_vector_type(8))) _Float16 half8;
typedef __attribute__((ext_vector_type(4))) float f32x4;

#define T_STEPS 24
#define N_NODES 325
#define RS_T 20800       // N*H elements per t
#define B_STRIDE 499200  // T*N*H elements per b
#define HLAST_OFF 31948800

__device__ __forceinline__ float fsigmoid(float x) {
    return __builtin_amdgcn_rcpf(1.0f + __expf(-x));
}
__device__ __forceinline__ float ftanh_f(float x) {
    return 1.0f - 2.0f * __builtin_amdgcn_rcpf(1.0f + __expf(2.0f * x));
}
__device__ __forceinline__ half4 cvt4(f32x4 a) {
    half4 r;
    r[0] = (_Float16)a[0]; r[1] = (_Float16)a[1];
    r[2] = (_Float16)a[2]; r[3] = (_Float16)a[3];
    return r;
}
__device__ __forceinline__ half8 cvt8(f32x4 a, f32x4 b) {
    half8 r;
    r[0]=(_Float16)a[0]; r[1]=(_Float16)a[1]; r[2]=(_Float16)a[2]; r[3]=(_Float16)a[3];
    r[4]=(_Float16)b[0]; r[5]=(_Float16)b[1]; r[6]=(_Float16)b[2]; r[7]=(_Float16)b[3];
    return r;
}

// R15 = R14 + weight B-frags hoisted into registers (read from LDS ONCE after
// the staging barrier). R14 counter math: 96KB of the 128KB LDS reads per
// block-step were the loop-invariant weight frags re-read 24x per wave —
// ~45% of wall on the LDS pipe. ds_read results can't be rematerialized, so
// under the (512,4) cap (128 VGPR, preserves 16 waves/CU) they must stay
// resident. Per-wave LDS reads per step: 16 -> 4.
__global__ __launch_bounds__(512, 4) void gru_wreg_kernel(
    const float* __restrict__ data,   // [B,T,N,F]
    const float* __restrict__ h0,     // [B,N,H]
    const float* __restrict__ w_ih,   // [192,64]
    const float* __restrict__ w_hh,   // [192,64]
    const float* __restrict__ b_ih,   // [192]
    const float* __restrict__ b_hh,   // [192]
    float* __restrict__ out)          // [B,T,N,H] ++ [B,N,H]
{
    const int tid  = threadIdx.x;
    const int lane = tid & 63;
    const int wv   = tid >> 6;        // 0..7
    const int tt   = wv >> 2;         // row-tile half (0/1)
    const int cl   = lane & 15;
    const int kg   = lane >> 4;
    const int c0   = (wv & 3) * 16;
    const int row0 = blockIdx.x * 32;

    __shared__ __align__(16) char wlds[2][192 * 128]; // weights f16 swizzled (48K)
    __shared__ __align__(16) char hlds[2][32 * 128];  // h dbuf f16 swizzled (8K)
    __shared__ __align__(16) char xlds[2][32 * 128];  // x dbuf f16 swizzled (8K)

    // ---- loader mapping: thread -> one f32x4 of the 32x64 x-tile ----
    const int lrow = tid >> 4;                    // 0..31
    const int lcol = tid & 15;                    // 4-float granule
    const int lxrow = row0 + lrow;
    const int lgbase = (lxrow / N_NODES) * B_STRIDE + (lxrow % N_NODES) * 64 + lcol * 4;
    const int lwoff  = lrow * 128 + ((lcol * 8) ^ ((lrow & 7) << 4)); // 8B granule

    // ---- issue x[0] early (rides under weight staging) ----
    const f32x4 x0t = *(const f32x4*)(data + lgbase);

    // ---- stage weights to LDS (f16, swizzled): 1536 chunks / 512 thr ----
#pragma unroll
    for (int mat = 0; mat < 2; ++mat) {
        const float* src = (mat == 0) ? w_ih : w_hh;
#pragma unroll
        for (int it = 0; it < 3; ++it) {
            const int c = it * 512 + tid;         // 0..1535
            const int n = c >> 3, j = c & 7;
            const f32x4 lo = *(const f32x4*)(src + n * 64 + j * 8);
            const f32x4 hi = *(const f32x4*)(src + n * 64 + j * 8 + 4);
            const int off = n * 128 + ((j * 16) ^ ((n & 7) << 4));
            *(half8*)(&wlds[mat][0] + off) = cvt8(lo, hi);
        }
    }
    // ---- stage h0 tile (32 rows) into hlds[0] ----
    {
        const int m = tid >> 4, c4 = (tid & 15) * 4;
        const f32x4 v = *(const f32x4*)(h0 + (row0 + m) * 64 + c4);
        const int off = m * 128 + ((c4 * 2) ^ ((m & 7) << 4));
        *(half4*)(&hlds[0][0] + off) = cvt4(v);
    }
    // ---- publish x[0] into slot 0; issue prefetch of x[1] ----
    *(half4*)(&xlds[0][0] + lwoff) = cvt4(x0t);
    f32x4 pfA = *(const f32x4*)(data + lgbase + RS_T);
    f32x4 pfB;
    __syncthreads();

    // ---- loop-invariant LDS byte offsets ----
    const int wsw  = ((c0 + cl) & 7) << 4;
    const int wof0 = (c0 + cl) * 128 + ((     kg * 16) ^ wsw);
    const int wof1 = (c0 + cl) * 128 + ((64 + kg * 16) ^ wsw);
    const int arow = tt * 16 + cl;                 // A-frag source row (tt half)
    const int hsw  = (cl & 7) << 4;                // +16 preserves &7
    const int hroff0 = arow * 128 + ((     kg * 16) ^ hsw);
    const int hroff1 = arow * 128 + ((64 + kg * 16) ^ hsw);

    // ---- weight B-frags: read ONCE, live in registers all 24 steps ----
    const half8 wr0 = *(const half8*)(&wlds[0][0] + wof0);
    const half8 wr1 = *(const half8*)(&wlds[0][0] + wof1);
    const half8 wz0 = *(const half8*)(&wlds[0][0] + wof0 + 8192);
    const half8 wz1 = *(const half8*)(&wlds[0][0] + wof1 + 8192);
    const half8 wn0 = *(const half8*)(&wlds[0][0] + wof0 + 16384);
    const half8 wn1 = *(const half8*)(&wlds[0][0] + wof1 + 16384);
    const half8 ur0 = *(const half8*)(&wlds[1][0] + wof0);
    const half8 ur1 = *(const half8*)(&wlds[1][0] + wof1);
    const half8 uz0 = *(const half8*)(&wlds[1][0] + wof0 + 8192);
    const half8 uz1 = *(const half8*)(&wlds[1][0] + wof1 + 8192);
    const half8 un0 = *(const half8*)(&wlds[1][0] + wof0 + 16384);
    const half8 un1 = *(const half8*)(&wlds[1][0] + wof1 + 16384);

    // ---- bias scalars (vectors built per step; compiler may hoist) ----
    const float bc0 = b_ih[      c0 + cl] + b_hh[      c0 + cl];
    const float bc1 = b_ih[ 64 + c0 + cl] + b_hh[ 64 + c0 + cl];
    const float bi2 = b_ih[128 + c0 + cl];
    const float bh2 = b_hh[128 + c0 + cl];

    // ---- per-lane h master copy + addressing (rows of the tt half) ----
    const int hb0 = (row0 + tt * 16 + kg * 4) * 64 + c0 + cl;
    float hreg[4];
#pragma unroll
    for (int r = 0; r < 4; ++r) hreg[r] = h0[hb0 + 64 * r];
    int obase[4];
#pragma unroll
    for (int r = 0; r < 4; ++r) {
        const int row = row0 + tt * 16 + kg * 4 + r;
        const int b = row / N_NODES, n = row % N_NODES;
        obase[r] = b * B_STRIDE + n * 64 + c0 + cl;
    }

    // One GRU step (slot = t&1). Weight frags come from registers now.
    auto gru_step = [&](int t, int slot, f32x4& pfw, f32x4& pfl) {
        const half8 xa0 = *(const half8*)(&xlds[slot][0] + hroff0);
        const half8 xa1 = *(const half8*)(&xlds[slot][0] + hroff1);
        const int cb = t & 1;
        const half8 hA0 = *(const half8*)(&hlds[cb][0] + hroff0);
        const half8 hA1 = *(const half8*)(&hlds[cb][0] + hroff1);

        // publish x[t+1] to the other slot, then issue x[t+2]
        if (t + 1 < T_STEPS)
            *(half4*)(&xlds[slot ^ 1][0] + lwoff) = cvt4(pfw);
        const int tl = (t + 2 < T_STEPS) ? t + 2 : T_STEPS - 1;
        pfl = *(const f32x4*)(data + lgbase + tl * RS_T);

        const f32x4 bR4  = {bc0, bc0, bc0, bc0};
        const f32x4 bZ4  = {bc1, bc1, bc1, bc1};
        const f32x4 bNX4 = {bi2, bi2, bi2, bi2};
        const f32x4 bNH4 = {bh2, bh2, bh2, bh2};

        // ---- 12 MFMAs (B operands register-resident) ----
        f32x4 aR  = __builtin_amdgcn_mfma_f32_16x16x32_f16(xa0, wr0, bR4,  0, 0, 0);
        f32x4 aZ  = __builtin_amdgcn_mfma_f32_16x16x32_f16(xa0, wz0, bZ4,  0, 0, 0);
        f32x4 aNX = __builtin_amdgcn_mfma_f32_16x16x32_f16(xa0, wn0, bNX4, 0, 0, 0);
        f32x4 aNH = __builtin_amdgcn_mfma_f32_16x16x32_f16(hA0, un0, bNH4, 0, 0, 0);
        aR  = __builtin_amdgcn_mfma_f32_16x16x32_f16(xa1, wr1, aR,  0, 0, 0);
        aZ  = __builtin_amdgcn_mfma_f32_16x16x32_f16(xa1, wz1, aZ,  0, 0, 0);
        aNX = __builtin_amdgcn_mfma_f32_16x16x32_f16(xa1, wn1, aNX, 0, 0, 0);
        aNH = __builtin_amdgcn_mfma_f32_16x16x32_f16(hA1, un1, aNH, 0, 0, 0);
        aR  = __builtin_amdgcn_mfma_f32_16x16x32_f16(hA0, ur0, aR,  0, 0, 0);
        aZ  = __builtin_amdgcn_mfma_f32_16x16x32_f16(hA0, uz0, aZ,  0, 0, 0);
        aR  = __builtin_amdgcn_mfma_f32_16x16x32_f16(hA1, ur1, aR,  0, 0, 0);
        aZ  = __builtin_amdgcn_mfma_f32_16x16x32_f16(hA1, uz1, aZ,  0, 0, 0);

        // ---- gates + update + store ----
        float hn[4];
#pragma unroll
        for (int r = 0; r < 4; ++r) {
            const float rg = fsigmoid(aR[r]);
            const float zg = fsigmoid(aZ[r]);
            const float cd = ftanh_f(aNX[r] + rg * aNH[r]);
            hn[r] = cd + zg * (hreg[r] - cd);
            hreg[r] = hn[r];
            out[t * RS_T + obase[r]] = hn[r];
        }

        // ---- publish h for t+1, lgkm-only barrier ----
        if (t + 1 < T_STEPS) {
            const int nb = (t + 1) & 1;
#pragma unroll
            for (int r = 0; r < 4; ++r) {
                const int mrow = tt * 16 + kg * 4 + r;
                const int off = mrow * 128 + (((c0 + cl) * 2) ^ ((mrow & 7) << 4));
                *(_Float16*)(&hlds[nb][0] + off) = (_Float16)hn[r];
            }
            asm volatile("s_waitcnt lgkmcnt(0)" ::: "memory");
            __builtin_amdgcn_s_barrier();
            __builtin_amdgcn_sched_barrier(0);
        }
    };

#pragma unroll 1
    for (int tb = 0; tb < T_STEPS; tb += 2) {
        gru_step(tb,     0, pfA, pfB);   // even: publish pfA, load pfB
        gru_step(tb + 1, 1, pfB, pfA);   // odd:  publish pfB, load pfA
    }

    // h_last
#pragma unroll
    for (int r = 0; r < 4; ++r)
        out[HLAST_OFF + hb0 + 64 * r] = hreg[r];
}

extern "C" void kernel_launch(void* const* d_in, const int* in_sizes, int n_in,
                              void* d_out, int out_size, void* d_ws, size_t ws_size,
                              hipStream_t stream) {
    const float* data = (const float*)d_in[1];
    const float* h0   = (const float*)d_in[2];
    const float* w_ih = (const float*)d_in[3];
    const float* w_hh = (const float*)d_in[4];
    const float* b_ih = (const float*)d_in[5];
    const float* b_hh = (const float*)d_in[6];
    float* out = (float*)d_out;

    // 20800 rows / 32 per block = 650 blocks, 8 waves each
    gru_wreg_kernel<<<dim3(650), dim3(512), 0, stream>>>(
        data, h0, w_ih, w_hh, b_ih, b_hh, out);
}

// Round 16
// 69.547 us; speedup vs baseline: 1.0350x; 1.0350x over previous
//
#include <hip/hip_runtime.h>

typedef __attribute__((ext_vector_type(4))) _Float16 half4;
typedef __attribute__((ext_vector_type(8))) _Float16 half8;
typedef __attribute__((ext_vector_type(4))) float f32x4;

#define T_STEPS 24
#define N_NODES 325
#define RS_T 20800       // N*H elements per t
#define B_STRIDE 499200  // T*N*H elements per b
#define HLAST_OFF 31948800

__device__ __forceinline__ float fsigmoid(float x) {
    return __builtin_amdgcn_rcpf(1.0f + __expf(-x));
}
__device__ __forceinline__ float ftanh_f(float x) {
    return 1.0f - 2.0f * __builtin_amdgcn_rcpf(1.0f + __expf(2.0f * x));
}
__device__ __forceinline__ half4 cvt4(f32x4 a) {
    half4 r;
    r[0] = (_Float16)a[0]; r[1] = (_Float16)a[1];
    r[2] = (_Float16)a[2]; r[3] = (_Float16)a[3];
    return r;
}
__device__ __forceinline__ half8 cvt8(f32x4 a, f32x4 b) {
    half8 r;
    r[0]=(_Float16)a[0]; r[1]=(_Float16)a[1]; r[2]=(_Float16)a[2]; r[3]=(_Float16)a[3];
    r[4]=(_Float16)b[0]; r[5]=(_Float16)b[1]; r[6]=(_Float16)b[2]; r[7]=(_Float16)b[3];
    return r;
}
// Register-only pin: value is opaquely "modified" -> cannot be rematerialized
// from LDS, cannot be sunk; forces true register residency across the loop.
__device__ __forceinline__ void rpin(half8& x) { asm volatile("" : "+v"(x)); }

// R16 = R14 + weight frags FORCED register-resident via per-iteration
// register-only pins. (R15 post-mortem: the per-step memory-clobber barrier
// asm legally blocks LICM of LDS loads — source hoisting alone gets undone.)
// Per-wave LDS reads per step: 16 -> 4. Everything else R14 byte-for-byte.
__global__ __launch_bounds__(512, 2) void gru_wpin_kernel(
    const float* __restrict__ data,   // [B,T,N,F]
    const float* __restrict__ h0,     // [B,N,H]
    const float* __restrict__ w_ih,   // [192,64]
    const float* __restrict__ w_hh,   // [192,64]
    const float* __restrict__ b_ih,   // [192]
    const float* __restrict__ b_hh,   // [192]
    float* __restrict__ out)          // [B,T,N,H] ++ [B,N,H]
{
    const int tid  = threadIdx.x;
    const int lane = tid & 63;
    const int wv   = tid >> 6;        // 0..7
    const int tt   = wv >> 2;         // row-tile half (0/1)
    const int cl   = lane & 15;
    const int kg   = lane >> 4;
    const int c0   = (wv & 3) * 16;
    const int row0 = blockIdx.x * 32;

    __shared__ __align__(16) char wlds[2][192 * 128]; // weights f16 swizzled (48K)
    __shared__ __align__(16) char hlds[2][32 * 128];  // h dbuf f16 swizzled (8K)
    __shared__ __align__(16) char xlds[2][32 * 128];  // x dbuf f16 swizzled (8K)

    // ---- loader mapping: thread -> one f32x4 of the 32x64 x-tile ----
    const int lrow = tid >> 4;                    // 0..31
    const int lcol = tid & 15;                    // 4-float granule
    const int lxrow = row0 + lrow;
    const int lgbase = (lxrow / N_NODES) * B_STRIDE + (lxrow % N_NODES) * 64 + lcol * 4;
    const int lwoff  = lrow * 128 + ((lcol * 8) ^ ((lrow & 7) << 4)); // 8B granule

    // ---- issue x[0] early (rides under weight staging) ----
    const f32x4 x0t = *(const f32x4*)(data + lgbase);

    // ---- stage weights to LDS (f16, swizzled): 1536 chunks / 512 thr ----
#pragma unroll
    for (int mat = 0; mat < 2; ++mat) {
        const float* src = (mat == 0) ? w_ih : w_hh;
#pragma unroll
        for (int it = 0; it < 3; ++it) {
            const int c = it * 512 + tid;         // 0..1535
            const int n = c >> 3, j = c & 7;
            const f32x4 lo = *(const f32x4*)(src + n * 64 + j * 8);
            const f32x4 hi = *(const f32x4*)(src + n * 64 + j * 8 + 4);
            const int off = n * 128 + ((j * 16) ^ ((n & 7) << 4));
            *(half8*)(&wlds[mat][0] + off) = cvt8(lo, hi);
        }
    }
    // ---- stage h0 tile (32 rows) into hlds[0] ----
    {
        const int m = tid >> 4, c4 = (tid & 15) * 4;
        const f32x4 v = *(const f32x4*)(h0 + (row0 + m) * 64 + c4);
        const int off = m * 128 + ((c4 * 2) ^ ((m & 7) << 4));
        *(half4*)(&hlds[0][0] + off) = cvt4(v);
    }
    // ---- publish x[0] into slot 0; issue prefetch of x[1] ----
    *(half4*)(&xlds[0][0] + lwoff) = cvt4(x0t);
    f32x4 pfA = *(const f32x4*)(data + lgbase + RS_T);
    f32x4 pfB;
    __syncthreads();

    // ---- loop-invariant LDS byte offsets ----
    const int wsw  = ((c0 + cl) & 7) << 4;
    const int wof0 = (c0 + cl) * 128 + ((     kg * 16) ^ wsw);
    const int wof1 = (c0 + cl) * 128 + ((64 + kg * 16) ^ wsw);
    const int arow = tt * 16 + cl;                 // A-frag source row (tt half)
    const int hsw  = (cl & 7) << 4;                // +16 preserves &7
    const int hroff0 = arow * 128 + ((     kg * 16) ^ hsw);
    const int hroff1 = arow * 128 + ((64 + kg * 16) ^ hsw);

    // ---- weight B-frags: read ONCE; pinned every iteration below ----
    half8 wr0 = *(const half8*)(&wlds[0][0] + wof0);
    half8 wr1 = *(const half8*)(&wlds[0][0] + wof1);
    half8 wz0 = *(const half8*)(&wlds[0][0] + wof0 + 8192);
    half8 wz1 = *(const half8*)(&wlds[0][0] + wof1 + 8192);
    half8 wn0 = *(const half8*)(&wlds[0][0] + wof0 + 16384);
    half8 wn1 = *(const half8*)(&wlds[0][0] + wof1 + 16384);
    half8 ur0 = *(const half8*)(&wlds[1][0] + wof0);
    half8 ur1 = *(const half8*)(&wlds[1][0] + wof1);
    half8 uz0 = *(const half8*)(&wlds[1][0] + wof0 + 8192);
    half8 uz1 = *(const half8*)(&wlds[1][0] + wof1 + 8192);
    half8 un0 = *(const half8*)(&wlds[1][0] + wof0 + 16384);
    half8 un1 = *(const half8*)(&wlds[1][0] + wof1 + 16384);

    // ---- bias scalars ----
    const float bc0 = b_ih[      c0 + cl] + b_hh[      c0 + cl];
    const float bc1 = b_ih[ 64 + c0 + cl] + b_hh[ 64 + c0 + cl];
    const float bi2 = b_ih[128 + c0 + cl];
    const float bh2 = b_hh[128 + c0 + cl];

    // ---- per-lane h master copy + addressing (rows of the tt half) ----
    const int hb0 = (row0 + tt * 16 + kg * 4) * 64 + c0 + cl;
    float hreg[4];
#pragma unroll
    for (int r = 0; r < 4; ++r) hreg[r] = h0[hb0 + 64 * r];
    int obase[4];
#pragma unroll
    for (int r = 0; r < 4; ++r) {
        const int row = row0 + tt * 16 + kg * 4 + r;
        const int b = row / N_NODES, n = row % N_NODES;
        obase[r] = b * B_STRIDE + n * 64 + c0 + cl;
    }

    // One GRU step (slot = t&1). Weight frags are pinned registers.
    auto gru_step = [&](int t, int slot, f32x4& pfw, f32x4& pfl) {
        // re-pin: compiler cannot substitute an LDS re-read for these values
        rpin(wr0); rpin(wr1); rpin(wz0); rpin(wz1); rpin(wn0); rpin(wn1);
        rpin(ur0); rpin(ur1); rpin(uz0); rpin(uz1); rpin(un0); rpin(un1);

        const half8 xa0 = *(const half8*)(&xlds[slot][0] + hroff0);
        const half8 xa1 = *(const half8*)(&xlds[slot][0] + hroff1);
        const int cb = t & 1;
        const half8 hA0 = *(const half8*)(&hlds[cb][0] + hroff0);
        const half8 hA1 = *(const half8*)(&hlds[cb][0] + hroff1);

        // publish x[t+1] to the other slot, then issue x[t+2]
        if (t + 1 < T_STEPS)
            *(half4*)(&xlds[slot ^ 1][0] + lwoff) = cvt4(pfw);
        const int tl = (t + 2 < T_STEPS) ? t + 2 : T_STEPS - 1;
        pfl = *(const f32x4*)(data + lgbase + tl * RS_T);

        const f32x4 bR4  = {bc0, bc0, bc0, bc0};
        const f32x4 bZ4  = {bc1, bc1, bc1, bc1};
        const f32x4 bNX4 = {bi2, bi2, bi2, bi2};
        const f32x4 bNH4 = {bh2, bh2, bh2, bh2};

        // ---- 12 MFMAs (B operands register-resident) ----
        f32x4 aR  = __builtin_amdgcn_mfma_f32_16x16x32_f16(xa0, wr0, bR4,  0, 0, 0);
        f32x4 aZ  = __builtin_amdgcn_mfma_f32_16x16x32_f16(xa0, wz0, bZ4,  0, 0, 0);
        f32x4 aNX = __builtin_amdgcn_mfma_f32_16x16x32_f16(xa0, wn0, bNX4, 0, 0, 0);
        f32x4 aNH = __builtin_amdgcn_mfma_f32_16x16x32_f16(hA0, un0, bNH4, 0, 0, 0);
        aR  = __builtin_amdgcn_mfma_f32_16x16x32_f16(xa1, wr1, aR,  0, 0, 0);
        aZ  = __builtin_amdgcn_mfma_f32_16x16x32_f16(xa1, wz1, aZ,  0, 0, 0);
        aNX = __builtin_amdgcn_mfma_f32_16x16x32_f16(xa1, wn1, aNX, 0, 0, 0);
        aNH = __builtin_amdgcn_mfma_f32_16x16x32_f16(hA1, un1, aNH, 0, 0, 0);
        aR  = __builtin_amdgcn_mfma_f32_16x16x32_f16(hA0, ur0, aR,  0, 0, 0);
        aZ  = __builtin_amdgcn_mfma_f32_16x16x32_f16(hA0, uz0, aZ,  0, 0, 0);
        aR  = __builtin_amdgcn_mfma_f32_16x16x32_f16(hA1, ur1, aR,  0, 0, 0);
        aZ  = __builtin_amdgcn_mfma_f32_16x16x32_f16(hA1, uz1, aZ,  0, 0, 0);

        // ---- gates + update + store ----
        float hn[4];
#pragma unroll
        for (int r = 0; r < 4; ++r) {
            const float rg = fsigmoid(aR[r]);
            const float zg = fsigmoid(aZ[r]);
            const float cd = ftanh_f(aNX[r] + rg * aNH[r]);
            hn[r] = cd + zg * (hreg[r] - cd);
            hreg[r] = hn[r];
            out[t * RS_T + obase[r]] = hn[r];
        }

        // ---- publish h for t+1, lgkm-only barrier ----
        if (t + 1 < T_STEPS) {
            const int nb = (t + 1) & 1;
#pragma unroll
            for (int r = 0; r < 4; ++r) {
                const int mrow = tt * 16 + kg * 4 + r;
                const int off = mrow * 128 + (((c0 + cl) * 2) ^ ((mrow & 7) << 4));
                *(_Float16*)(&hlds[nb][0] + off) = (_Float16)hn[r];
            }
            asm volatile("s_waitcnt lgkmcnt(0)" ::: "memory");
            __builtin_amdgcn_s_barrier();
            __builtin_amdgcn_sched_barrier(0);
        }
    };

#pragma unroll 1
    for (int tb = 0; tb < T_STEPS; tb += 2) {
        gru_step(tb,     0, pfA, pfB);   // even: publish pfA, load pfB
        gru_step(tb + 1, 1, pfB, pfA);   // odd:  publish pfB, load pfA
    }

    // h_last
#pragma unroll
    for (int r = 0; r < 4; ++r)
        out[HLAST_OFF + hb0 + 64 * r] = hreg[r];
}

extern "C" void kernel_launch(void* const* d_in, const int* in_sizes, int n_in,
                              void* d_out, int out_size, void* d_ws, size_t ws_size,
                              hipStream_t stream) {
    const float* data = (const float*)d_in[1];
    const float* h0   = (const float*)d_in[2];
    const float* w_ih = (const float*)d_in[3];
    const float* w_hh = (const float*)d_in[4];
    const float* b_ih = (const float*)d_in[5];
    const float* b_hh = (const float*)d_in[6];
    float* out = (float*)d_out;

    // 20800 rows / 32 per block = 650 blocks, 8 waves each
    gru_wpin_kernel<<<dim3(650), dim3(512), 0, stream>>>(
        data, h0, w_ih, w_hh, b_ih, b_hh, out);
}

// Round 17
// 65.122 us; speedup vs baseline: 1.1053x; 1.0680x over previous
//
#include <hip/hip_runtime.h>

typedef __attribute__((ext_vector_type(4))) _Float16 half4;
typedef __attribute__((ext_vector_type(8))) _Float16 half8;
typedef __attribute__((ext_vector_type(4))) float f32x4;

#define T_STEPS 24
#define N_NODES 325
#define RS_T 20800       // N*H elements per t
#define B_STRIDE 499200  // T*N*H elements per b
#define HLAST_OFF 31948800

__device__ __forceinline__ float fsigmoid(float x) {
    return __builtin_amdgcn_rcpf(1.0f + __expf(-x));
}
__device__ __forceinline__ float ftanh_f(float x) {
    return 1.0f - 2.0f * __builtin_amdgcn_rcpf(1.0f + __expf(2.0f * x));
}
__device__ __forceinline__ half4 cvt4(f32x4 a) {
    half4 r;
    r[0] = (_Float16)a[0]; r[1] = (_Float16)a[1];
    r[2] = (_Float16)a[2]; r[3] = (_Float16)a[3];
    return r;
}
__device__ __forceinline__ half8 cvt8(f32x4 a, f32x4 b) {
    half8 r;
    r[0]=(_Float16)a[0]; r[1]=(_Float16)a[1]; r[2]=(_Float16)a[2]; r[3]=(_Float16)a[3];
    r[4]=(_Float16)b[0]; r[5]=(_Float16)b[1]; r[6]=(_Float16)b[2]; r[7]=(_Float16)b[3];
    return r;
}
// AGPR pin: value becomes asm-defined (NOT rematerializable from LDS) and is
// placed in the AGPR file. gfx950 MFMA A/B operands are AV-class (VGPR or
// AGPR), so intrinsics consume it in place — no per-use copies.
__device__ __forceinline__ void apin(half8& x) { asm volatile("" : "+a"(x)); }

// R17 = R14 + (1) waves_per_eu(4,4): compiler's occupancy target clamped to
// the LDS-imposed 4 waves/SIMD -> 128-reg budget, no remat pressure;
// (2) 12 weight B-frags pinned into AGPRs (48 AGPRs), read from LDS once.
// Per-wave in-loop LDS reads: 16 -> 4 (x + h A-frags only).
__global__ __launch_bounds__(512)
__attribute__((amdgpu_waves_per_eu(4, 4)))
void gru_agpr_kernel(
    const float* __restrict__ data,   // [B,T,N,F]
    const float* __restrict__ h0,     // [B,N,H]
    const float* __restrict__ w_ih,   // [192,64]
    const float* __restrict__ w_hh,   // [192,64]
    const float* __restrict__ b_ih,   // [192]
    const float* __restrict__ b_hh,   // [192]
    float* __restrict__ out)          // [B,T,N,H] ++ [B,N,H]
{
    const int tid  = threadIdx.x;
    const int lane = tid & 63;
    const int wv   = tid >> 6;        // 0..7
    const int tt   = wv >> 2;         // row-tile half (0/1)
    const int cl   = lane & 15;
    const int kg   = lane >> 4;
    const int c0   = (wv & 3) * 16;
    const int row0 = blockIdx.x * 32;

    __shared__ __align__(16) char wlds[2][192 * 128]; // weights f16 swizzled (48K)
    __shared__ __align__(16) char hlds[2][32 * 128];  // h dbuf f16 swizzled (8K)
    __shared__ __align__(16) char xlds[2][32 * 128];  // x dbuf f16 swizzled (8K)

    // ---- loader mapping: thread -> one f32x4 of the 32x64 x-tile ----
    const int lrow = tid >> 4;                    // 0..31
    const int lcol = tid & 15;                    // 4-float granule
    const int lxrow = row0 + lrow;
    const int lgbase = (lxrow / N_NODES) * B_STRIDE + (lxrow % N_NODES) * 64 + lcol * 4;
    const int lwoff  = lrow * 128 + ((lcol * 8) ^ ((lrow & 7) << 4)); // 8B granule

    // ---- issue x[0] early (rides under weight staging) ----
    const f32x4 x0t = *(const f32x4*)(data + lgbase);

    // ---- stage weights to LDS (f16, swizzled): 1536 chunks / 512 thr ----
#pragma unroll
    for (int mat = 0; mat < 2; ++mat) {
        const float* src = (mat == 0) ? w_ih : w_hh;
#pragma unroll
        for (int it = 0; it < 3; ++it) {
            const int c = it * 512 + tid;         // 0..1535
            const int n = c >> 3, j = c & 7;
            const f32x4 lo = *(const f32x4*)(src + n * 64 + j * 8);
            const f32x4 hi = *(const f32x4*)(src + n * 64 + j * 8 + 4);
            const int off = n * 128 + ((j * 16) ^ ((n & 7) << 4));
            *(half8*)(&wlds[mat][0] + off) = cvt8(lo, hi);
        }
    }
    // ---- stage h0 tile (32 rows) into hlds[0] ----
    {
        const int m = tid >> 4, c4 = (tid & 15) * 4;
        const f32x4 v = *(const f32x4*)(h0 + (row0 + m) * 64 + c4);
        const int off = m * 128 + ((c4 * 2) ^ ((m & 7) << 4));
        *(half4*)(&hlds[0][0] + off) = cvt4(v);
    }
    // ---- publish x[0] into slot 0; issue prefetch of x[1] ----
    *(half4*)(&xlds[0][0] + lwoff) = cvt4(x0t);
    f32x4 pfA = *(const f32x4*)(data + lgbase + RS_T);
    f32x4 pfB;
    __syncthreads();

    // ---- loop-invariant LDS byte offsets ----
    const int wsw  = ((c0 + cl) & 7) << 4;
    const int wof0 = (c0 + cl) * 128 + ((     kg * 16) ^ wsw);
    const int wof1 = (c0 + cl) * 128 + ((64 + kg * 16) ^ wsw);
    const int arow = tt * 16 + cl;                 // A-frag source row (tt half)
    const int hsw  = (cl & 7) << 4;                // +16 preserves &7
    const int hroff0 = arow * 128 + ((     kg * 16) ^ hsw);
    const int hroff1 = arow * 128 + ((64 + kg * 16) ^ hsw);

    // ---- weight B-frags: read ONCE from LDS, pinned into AGPRs ----
    half8 wr0 = *(const half8*)(&wlds[0][0] + wof0);
    half8 wr1 = *(const half8*)(&wlds[0][0] + wof1);
    half8 wz0 = *(const half8*)(&wlds[0][0] + wof0 + 8192);
    half8 wz1 = *(const half8*)(&wlds[0][0] + wof1 + 8192);
    half8 wn0 = *(const half8*)(&wlds[0][0] + wof0 + 16384);
    half8 wn1 = *(const half8*)(&wlds[0][0] + wof1 + 16384);
    half8 ur0 = *(const half8*)(&wlds[1][0] + wof0);
    half8 ur1 = *(const half8*)(&wlds[1][0] + wof1);
    half8 uz0 = *(const half8*)(&wlds[1][0] + wof0 + 8192);
    half8 uz1 = *(const half8*)(&wlds[1][0] + wof1 + 8192);
    half8 un0 = *(const half8*)(&wlds[1][0] + wof0 + 16384);
    half8 un1 = *(const half8*)(&wlds[1][0] + wof1 + 16384);
    apin(wr0); apin(wr1); apin(wz0); apin(wz1); apin(wn0); apin(wn1);
    apin(ur0); apin(ur1); apin(uz0); apin(uz1); apin(un0); apin(un1);

    // ---- bias scalars ----
    const float bc0 = b_ih[      c0 + cl] + b_hh[      c0 + cl];
    const float bc1 = b_ih[ 64 + c0 + cl] + b_hh[ 64 + c0 + cl];
    const float bi2 = b_ih[128 + c0 + cl];
    const float bh2 = b_hh[128 + c0 + cl];

    // ---- per-lane h master copy + addressing (rows of the tt half) ----
    const int hb0 = (row0 + tt * 16 + kg * 4) * 64 + c0 + cl;
    float hreg[4];
#pragma unroll
    for (int r = 0; r < 4; ++r) hreg[r] = h0[hb0 + 64 * r];
    int obase[4];
#pragma unroll
    for (int r = 0; r < 4; ++r) {
        const int row = row0 + tt * 16 + kg * 4 + r;
        const int b = row / N_NODES, n = row % N_NODES;
        obase[r] = b * B_STRIDE + n * 64 + c0 + cl;
    }

    // One GRU step (slot = t&1). Weight frags live in AGPRs.
    auto gru_step = [&](int t, int slot, f32x4& pfw, f32x4& pfl) {
        const half8 xa0 = *(const half8*)(&xlds[slot][0] + hroff0);
        const half8 xa1 = *(const half8*)(&xlds[slot][0] + hroff1);
        const int cb = t & 1;
        const half8 hA0 = *(const half8*)(&hlds[cb][0] + hroff0);
        const half8 hA1 = *(const half8*)(&hlds[cb][0] + hroff1);

        // publish x[t+1] to the other slot, then issue x[t+2]
        if (t + 1 < T_STEPS)
            *(half4*)(&xlds[slot ^ 1][0] + lwoff) = cvt4(pfw);
        const int tl = (t + 2 < T_STEPS) ? t + 2 : T_STEPS - 1;
        pfl = *(const f32x4*)(data + lgbase + tl * RS_T);

        const f32x4 bR4  = {bc0, bc0, bc0, bc0};
        const f32x4 bZ4  = {bc1, bc1, bc1, bc1};
        const f32x4 bNX4 = {bi2, bi2, bi2, bi2};
        const f32x4 bNH4 = {bh2, bh2, bh2, bh2};

        // ---- 12 MFMAs (B operands AGPR-resident) ----
        f32x4 aR  = __builtin_amdgcn_mfma_f32_16x16x32_f16(xa0, wr0, bR4,  0, 0, 0);
        f32x4 aZ  = __builtin_amdgcn_mfma_f32_16x16x32_f16(xa0, wz0, bZ4,  0, 0, 0);
        f32x4 aNX = __builtin_amdgcn_mfma_f32_16x16x32_f16(xa0, wn0, bNX4, 0, 0, 0);
        f32x4 aNH = __builtin_amdgcn_mfma_f32_16x16x32_f16(hA0, un0, bNH4, 0, 0, 0);
        aR  = __builtin_amdgcn_mfma_f32_16x16x32_f16(xa1, wr1, aR,  0, 0, 0);
        aZ  = __builtin_amdgcn_mfma_f32_16x16x32_f16(xa1, wz1, aZ,  0, 0, 0);
        aNX = __builtin_amdgcn_mfma_f32_16x16x32_f16(xa1, wn1, aNX, 0, 0, 0);
        aNH = __builtin_amdgcn_mfma_f32_16x16x32_f16(hA1, un1, aNH, 0, 0, 0);
        aR  = __builtin_amdgcn_mfma_f32_16x16x32_f16(hA0, ur0, aR,  0, 0, 0);
        aZ  = __builtin_amdgcn_mfma_f32_16x16x32_f16(hA0, uz0, aZ,  0, 0, 0);
        aR  = __builtin_amdgcn_mfma_f32_16x16x32_f16(hA1, ur1, aR,  0, 0, 0);
        aZ  = __builtin_amdgcn_mfma_f32_16x16x32_f16(hA1, uz1, aZ,  0, 0, 0);

        // ---- gates + update + store ----
        float hn[4];
#pragma unroll
        for (int r = 0; r < 4; ++r) {
            const float rg = fsigmoid(aR[r]);
            const float zg = fsigmoid(aZ[r]);
            const float cd = ftanh_f(aNX[r] + rg * aNH[r]);
            hn[r] = cd + zg * (hreg[r] - cd);
            hreg[r] = hn[r];
            out[t * RS_T + obase[r]] = hn[r];
        }

        // ---- publish h for t+1, lgkm-only barrier ----
        if (t + 1 < T_STEPS) {
            const int nb = (t + 1) & 1;
#pragma unroll
            for (int r = 0; r < 4; ++r) {
                const int mrow = tt * 16 + kg * 4 + r;
                const int off = mrow * 128 + (((c0 + cl) * 2) ^ ((mrow & 7) << 4));
                *(_Float16*)(&hlds[nb][0] + off) = (_Float16)hn[r];
            }
            asm volatile("s_waitcnt lgkmcnt(0)" ::: "memory");
            __builtin_amdgcn_s_barrier();
            __builtin_amdgcn_sched_barrier(0);
        }
    };

#pragma unroll 1
    for (int tb = 0; tb < T_STEPS; tb += 2) {
        gru_step(tb,     0, pfA, pfB);   // even: publish pfA, load pfB
        gru_step(tb + 1, 1, pfB, pfA);   // odd:  publish pfB, load pfA
    }

    // h_last
#pragma unroll
    for (int r = 0; r < 4; ++r)
        out[HLAST_OFF + hb0 + 64 * r] = hreg[r];
}

extern "C" void kernel_launch(void* const* d_in, const int* in_sizes, int n_in,
                              void* d_out, int out_size, void* d_ws, size_t ws_size,
                              hipStream_t stream) {
    const float* data = (const float*)d_in[1];
    const float* h0   = (const float*)d_in[2];
    const float* w_ih = (const float*)d_in[3];
    const float* w_hh = (const float*)d_in[4];
    const float* b_ih = (const float*)d_in[5];
    const float* b_hh = (const float*)d_in[6];
    float* out = (float*)d_out;

    // 20800 rows / 32 per block = 650 blocks, 8 waves each
    gru_agpr_kernel<<<dim3(650), dim3(512), 0, stream>>>(
        data, h0, w_ih, w_hh, b_ih, b_hh, out);
}